// Round 19
// baseline (189.958 us; speedup 1.0000x reference)
//
#include <hip/hip_runtime.h>
#include <hip/hip_bf16.h>

// MultiHeadAttention: B=4, S=2048, D_MODEL=512, N_HEAD=8, D_K=64
// Pipeline: ws memset hedge -> proj3 (BK=64, proven bit-transparent r17/r18) ->
// flash_attn (r15 verbatim: defer-max, 2 q-tiles/wave, KVBLK=32) -> out_gemm

typedef __attribute__((ext_vector_type(8))) short short8;
typedef __attribute__((ext_vector_type(4))) float f32x4;
typedef __attribute__((ext_vector_type(16))) float f32x16;
typedef __attribute__((ext_vector_type(4))) unsigned short u16x4;

union pack_t { int w[4]; short8 v; };

static __device__ __forceinline__ unsigned short f2bf(float x) {
  union { float f; unsigned u; } v; v.f = x;
  unsigned r = v.u + 0x7fffu + ((v.u >> 16) & 1u);
  return (unsigned short)(r >> 16);
}

static __device__ __forceinline__ short8 ld8(const unsigned short* p) {
  return *reinterpret_cast<const short8*>(p);
}

static __device__ __forceinline__ float vmax3(float a, float b, float c) {
  float r; asm("v_max3_f32 %0, %1, %2, %3" : "=v"(r) : "v"(a), "v"(b), "v"(c)); return r;
}

static __device__ __forceinline__ float vexp2(float x) {
  float r; asm("v_exp_f32 %0, %1" : "=v"(r) : "v"(x)); return r;
}

static __device__ __forceinline__ int cvtpk(float a, float b) {
  int r; asm("v_cvt_pk_bf16_f32 %0, %1, %2" : "=v"(r) : "v"(a), "v"(b)); return r;
}

// ---------------------------------------------------------------------------
// Fused projection GEMMs, BK=64 (barriers halved; output bit-identical to the
// BK=32 version — proven by the r17/r18 A/B giving identical downstream
// absmax). Epilogues r15-verified (coalesced u16x4).
// ---------------------------------------------------------------------------
__global__ __launch_bounds__(256) void proj3(
    const float* __restrict__ Xq, const float* __restrict__ Xk, const float* __restrict__ Xv,
    const float* __restrict__ Wq, const float* __restrict__ Wk, const float* __restrict__ Wv,
    const float* __restrict__ bq, const float* __restrict__ bk, const float* __restrict__ bv,
    unsigned short* __restrict__ Qh, unsigned short* __restrict__ Kh,
    unsigned short* __restrict__ Vt)
{
  const int z = blockIdx.z;
  const float* X = z == 0 ? Xq : z == 1 ? Xk : Xv;
  const float* W = z == 0 ? Wq : z == 1 ? Wk : Wv;
  const float* bias = z == 0 ? bq : z == 1 ? bk : bv;
  unsigned short* dst = z == 0 ? Qh : z == 1 ? Kh : Vt;
  const int vmode = (z == 2);
  const float oscale = z == 0 ? 0.1803368801f : 1.0f;  // (1/8)*log2(e)

  __shared__ unsigned short Al[128][72];
  __shared__ unsigned short Bl[128][72];
  const int tid = threadIdx.x;
  const int lane = tid & 63;
  const int g = lane >> 4, c = lane & 15;
  const int wave = tid >> 6;
  const int m0 = blockIdx.x * 128, n0 = blockIdx.y * 128;
  const int wm = (wave & 1) * 64, wn = (wave >> 1) * 64;
  f32x4 acc[4][4] = {};

  const int srow = tid >> 4;          // 0..15
  const int scol = (tid & 15) * 4;    // 0..60

  for (int k0 = 0; k0 < 512; k0 += 64) {
    __syncthreads();
#pragma unroll
    for (int p = 0; p < 8; ++p) {
      int row = p * 16 + srow;
      f32x4 xv = *reinterpret_cast<const f32x4*>(&X[(size_t)(m0 + row) * 512 + k0 + scol]);
      u16x4 xb = { f2bf(xv[0]), f2bf(xv[1]), f2bf(xv[2]), f2bf(xv[3]) };
      *reinterpret_cast<u16x4*>(&Al[row][scol]) = xb;
      f32x4 wv = *reinterpret_cast<const f32x4*>(&W[(size_t)(n0 + row) * 512 + k0 + scol]);
      u16x4 wb = { f2bf(wv[0]), f2bf(wv[1]), f2bf(wv[2]), f2bf(wv[3]) };
      *reinterpret_cast<u16x4*>(&Bl[row][scol]) = wb;
    }
    __syncthreads();
#pragma unroll
    for (int kk = 0; kk < 2; ++kk) {
      short8 af[4], bfr[4];
#pragma unroll
      for (int i = 0; i < 4; ++i) {
        af[i]  = ld8(&Al[wm + i * 16 + c][kk * 32 + g * 8]);
        bfr[i] = ld8(&Bl[wn + i * 16 + c][kk * 32 + g * 8]);
      }
      if (vmode) {
#pragma unroll
        for (int i = 0; i < 4; ++i)
#pragma unroll
          for (int j = 0; j < 4; ++j)
            acc[i][j] = __builtin_amdgcn_mfma_f32_16x16x32_bf16(af[i], bfr[j], acc[i][j], 0, 0, 0);
      } else {
#pragma unroll
        for (int i = 0; i < 4; ++i)
#pragma unroll
          for (int j = 0; j < 4; ++j)
            acc[i][j] = __builtin_amdgcn_mfma_f32_16x16x32_bf16(bfr[j], af[i], acc[i][j], 0, 0, 0);
      }
    }
  }

  if (!vmode) {
#pragma unroll
    for (int i = 0; i < 4; ++i) {
      int rowm = m0 + wm + i * 16 + c;
      int b = rowm >> 11, s = rowm & 2047;
#pragma unroll
      for (int j = 0; j < 4; ++j) {
        int nb = n0 + wn + j * 16 + g * 4;
        int h = nb >> 6, d = nb & 63;
        f32x4 bi = *reinterpret_cast<const f32x4*>(&bias[nb]);
        u16x4 o;
#pragma unroll
        for (int r = 0; r < 4; ++r) o[r] = f2bf((acc[i][j][r] + bi[r]) * oscale);
        *reinterpret_cast<u16x4*>(&dst[((size_t)((b * 8 + h) * 2048 + s)) * 64 + d]) = o;
      }
    }
  } else {
#pragma unroll
    for (int j = 0; j < 4; ++j) {
      int col = n0 + wn + j * 16 + c;
      float bcol = bias[col];
      int h = col >> 6, d = col & 63;
#pragma unroll
      for (int i = 0; i < 4; ++i) {
        int rowm = m0 + wm + i * 16 + g * 4;
        int b = rowm >> 11, s = rowm & 2047;
        u16x4 o;
#pragma unroll
        for (int r = 0; r < 4; ++r) o[r] = f2bf(acc[i][j][r] + bcol);
        *reinterpret_cast<u16x4*>(&dst[((size_t)((b * 8 + h) * 64 + d)) * 2048 + s]) = o;
      }
    }
  }
}

// ---------------------------------------------------------------------------
// flash_attn helpers (r13/r15-verified math, verbatim)
// ---------------------------------------------------------------------------
static __device__ __forceinline__ f32x16 qk_step(
    const short8* qf, short8 k0, short8 k1, short8 k2, short8 k3)
{
  f32x16 sp = {};
  sp = __builtin_amdgcn_mfma_f32_32x32x16_bf16(k0, qf[0], sp, 0, 0, 0);
  sp = __builtin_amdgcn_mfma_f32_32x32x16_bf16(k1, qf[1], sp, 0, 0, 0);
  sp = __builtin_amdgcn_mfma_f32_32x32x16_bf16(k2, qf[2], sp, 0, 0, 0);
  sp = __builtin_amdgcn_mfma_f32_32x32x16_bf16(k3, qf[3], sp, 0, 0, 0);
  return sp;
}

static __device__ __forceinline__ void pv_step(
    short8 v0, short8 v1, short8 v2, short8 v3,
    const pack_t& pf0, const pack_t& pf1, f32x16& acc0, f32x16& acc1)
{
  acc0 = __builtin_amdgcn_mfma_f32_32x32x16_bf16(v0, pf0.v, acc0, 0, 0, 0);
  acc1 = __builtin_amdgcn_mfma_f32_32x32x16_bf16(v1, pf0.v, acc1, 0, 0, 0);
  acc0 = __builtin_amdgcn_mfma_f32_32x32x16_bf16(v2, pf1.v, acc0, 0, 0, 0);
  acc1 = __builtin_amdgcn_mfma_f32_32x32x16_bf16(v3, pf1.v, acc1, 0, 0, 0);
}

static __device__ __forceinline__ void softmax_step(
    const f32x16& sp, float& mrun, float& lrun,
    f32x16& acc0, f32x16& acc1, pack_t& pf0, pack_t& pf1)
{
  float ta = vmax3(sp[0], sp[1], sp[2]);
  float tb = vmax3(sp[3], sp[4], sp[5]);
  float tc = vmax3(sp[6], sp[7], sp[8]);
  float td = vmax3(sp[9], sp[10], sp[11]);
  ta = vmax3(ta, sp[12], sp[13]);
  tb = vmax3(tb, sp[14], sp[15]);
  float tm = fmaxf(vmax3(ta, tb, tc), td);
  float tmx = fmaxf(tm, __shfl_xor(tm, 32));
  if (!__all(tmx <= mrun + 11.0f)) {   // defer-max: P bounded by 2^11 (verified)
    float mn = fmaxf(mrun, tmx);
    float alpha = vexp2(mrun - mn);
    mrun = mn; lrun *= alpha;
#pragma unroll
    for (int i = 0; i < 16; ++i) { acc0[i] *= alpha; acc1[i] *= alpha; }
  }
  float p[16];
  float s0 = 0.f, s1 = 0.f, s2 = 0.f, s3 = 0.f;
#pragma unroll
  for (int i = 0; i < 4; ++i) {
    p[4 * i]     = vexp2(sp[4 * i]     - mrun); s0 += p[4 * i];
    p[4 * i + 1] = vexp2(sp[4 * i + 1] - mrun); s1 += p[4 * i + 1];
    p[4 * i + 2] = vexp2(sp[4 * i + 2] - mrun); s2 += p[4 * i + 2];
    p[4 * i + 3] = vexp2(sp[4 * i + 3] - mrun); s3 += p[4 * i + 3];
  }
  lrun += (s0 + s1) + (s2 + s3);
#pragma unroll
  for (int w = 0; w < 4; ++w) {
    pf0.w[w] = cvtpk(p[2 * w],     p[2 * w + 1]);
    pf1.w[w] = cvtpk(p[8 + 2 * w], p[9 + 2 * w]);
  }
}

// ---------------------------------------------------------------------------
// Flash attention (r15 verbatim): two q-tiles per wave, defer-max softmax.
// ---------------------------------------------------------------------------
__global__ __launch_bounds__(256, 2) void flash_attn(
    const unsigned short* __restrict__ Qh, const unsigned short* __restrict__ Kh,
    const unsigned short* __restrict__ Vt, unsigned short* __restrict__ attn)
{
  __shared__ float Mred[2][2][64];
  __shared__ float Lred[2][2][64];
  __shared__ float AccO[2][64][64];
  const int lane = threadIdx.x & 63;
  const int wave = threadIdx.x >> 6;
  const int qt = wave & 1;
  const int kh = wave >> 1;
  const int lq = lane & 31;
  const int hi = lane >> 5;
  const int n = blockIdx.y * 16 + blockIdx.x;
  const int bh = 4 * (n & 7) + ((n >> 3) & 3);
  const int qw = (n >> 5) * 128 + qt * 64;
  const unsigned short* Qp = Qh + (size_t)bh * 2048 * 64;
  const unsigned short* Kp = Kh + (size_t)bh * 2048 * 64;
  const unsigned short* Vp = Vt + (size_t)bh * 64 * 2048;
  const int blq = (lq & 19) | ((lq & 4) << 1) | ((lq & 8) >> 1);

  short8 qfA[4], qfB[4];
#pragma unroll
  for (int ds = 0; ds < 4; ++ds) {
    qfA[ds] = ld8(Qp + (size_t)(qw + lq) * 64      + ds * 16 + hi * 8);
    qfB[ds] = ld8(Qp + (size_t)(qw + 32 + lq) * 64 + ds * 16 + hi * 8);
  }

  const unsigned short* Kb  = Kp + (size_t)(kh * 1024 + blq) * 64 + hi * 8;
  const unsigned short* Vb0 = Vp + (size_t)lq * 2048        + kh * 1024 + hi * 8;
  const unsigned short* Vb1 = Vp + (size_t)(32 + lq) * 2048 + kh * 1024 + hi * 8;

  short8 kf0, kf1, kf2, kf3, vf0, vf1, vf2, vf3;
#define LOADK(t) do {                                                       \
    const unsigned short* kp_ = Kb + (size_t)(t) * 2048;                    \
    kf0 = ld8(kp_); kf1 = ld8(kp_ + 16); kf2 = ld8(kp_ + 32);               \
    kf3 = ld8(kp_ + 48);                                                    \
  } while (0)
#define LOADV(t) do {                                                       \
    vf0 = ld8(Vb0 + (t) * 32);      vf1 = ld8(Vb1 + (t) * 32);              \
    vf2 = ld8(Vb0 + (t) * 32 + 16); vf3 = ld8(Vb1 + (t) * 32 + 16);         \
  } while (0)

  f32x16 accA0 = {}, accA1 = {}, accB0 = {}, accB1 = {};
  float mrunA = -1e30f, lrunA = 0.f;
  float mrunB = -1e30f, lrunB = 0.f;

  LOADK(0);
  LOADV(0);
  for (int t = 0; t < 32; ++t) {
    __builtin_amdgcn_s_setprio(1);
    f32x16 spA = qk_step(qfA, kf0, kf1, kf2, kf3);
    f32x16 spB = qk_step(qfB, kf0, kf1, kf2, kf3);
    __builtin_amdgcn_s_setprio(0);

    if (t < 31) LOADK(t + 1);

    pack_t pfA0, pfA1, pfB0, pfB1;
    softmax_step(spA, mrunA, lrunA, accA0, accA1, pfA0, pfA1);
    softmax_step(spB, mrunB, lrunB, accB0, accB1, pfB0, pfB1);

    __builtin_amdgcn_s_setprio(1);
    pv_step(vf0, vf1, vf2, vf3, pfA0, pfA1, accA0, accA1);
    pv_step(vf0, vf1, vf2, vf3, pfB0, pfB1, accB0, accB1);
    __builtin_amdgcn_s_setprio(0);

    if (t < 31) LOADV(t + 1);
  }
#undef LOADK
#undef LOADV

  float lfullA = lrunA + __shfl_xor(lrunA, 32);
  float lfullB = lrunB + __shfl_xor(lrunB, 32);
  if (lane < 32) {
    Mred[qt][kh][lq] = mrunA;      Lred[qt][kh][lq] = lfullA;
    Mred[qt][kh][32 + lq] = mrunB; Lred[qt][kh][32 + lq] = lfullB;
  }
  __syncthreads();
  float moA = Mred[qt][kh ^ 1][lq],      loA = Lred[qt][kh ^ 1][lq];
  float moB = Mred[qt][kh ^ 1][32 + lq], loB = Lred[qt][kh ^ 1][32 + lq];
  float mA = fmaxf(mrunA, moA);
  float mB = fmaxf(mrunB, moB);
  float ltotA = lfullA * vexp2(mrunA - mA) + loA * vexp2(moA - mA);
  float ltotB = lfullB * vexp2(mrunB - mB) + loB * vexp2(moB - mB);
  float scA = vexp2(mrunA - mA);
  float scB = vexp2(mrunB - mB);
#pragma unroll
  for (int i = 0; i < 16; ++i) {
    accA0[i] *= scA; accA1[i] *= scA;
    accB0[i] *= scB; accB1[i] *= scB;
  }
  if (kh == 1) {
#pragma unroll
    for (int i = 0; i < 16; ++i) {
      int d = (i & 3) + 8 * (i >> 2) + 4 * hi;
      AccO[qt][d][lq]           = accA0[i];
      AccO[qt][32 + d][lq]      = accA1[i];
      AccO[qt][d][32 + lq]      = accB0[i];
      AccO[qt][32 + d][32 + lq] = accB1[i];
    }
  }
  __syncthreads();
  if (kh == 0) {
#pragma unroll
    for (int i = 0; i < 16; ++i) {
      int d = (i & 3) + 8 * (i >> 2) + 4 * hi;
      AccO[qt][d][lq]           += accA0[i];
      AccO[qt][32 + d][lq]      += accA1[i];
      AccO[qt][d][32 + lq]      += accB0[i];
      AccO[qt][32 + d][32 + lq] += accB1[i];
    }
    float lt = (lane < 32) ? ltotA : ltotB;
    float rl = 1.0f / lt;
    const int b = bh >> 3, h = bh & 7;
    unsigned short* rowp = attn + ((size_t)(b * 2048 + qw + lane)) * 512 + h * 64;
#pragma unroll
    for (int d0 = 0; d0 < 64; d0 += 8) {
      u16x4 o0, o1;
#pragma unroll
      for (int j = 0; j < 4; ++j) {
        o0[j] = f2bf(AccO[qt][d0 + j][lane] * rl);
        o1[j] = f2bf(AccO[qt][d0 + 4 + j][lane] * rl);
      }
      *reinterpret_cast<u16x4*>(rowp + d0) = o0;
      *reinterpret_cast<u16x4*>(rowp + d0 + 4) = o1;
    }
  }
}

// ---------------------------------------------------------------------------
// Output projection (r15-verified, unchanged)
// ---------------------------------------------------------------------------
__global__ __launch_bounds__(256) void out_gemm(
    const unsigned short* __restrict__ A, const float* __restrict__ W,
    const float* __restrict__ bias, float* __restrict__ out)
{
  __shared__ unsigned short Al[128][40];
  __shared__ unsigned short Bl[128][40];
  const int tid = threadIdx.x;
  const int lane = tid & 63;
  const int g = lane >> 4, c = lane & 15;
  const int wave = tid >> 6;
  const int m0 = blockIdx.x * 128, n0 = blockIdx.y * 128;
  const int wm = (wave & 1) * 64, wn = (wave >> 1) * 64;
  f32x4 acc[4][4] = {};

  const int arow = tid >> 2;
  const int acol = (tid & 3) * 8;
  const int srow = tid >> 3;
  const int scol = (tid & 7) * 4;

  for (int k0 = 0; k0 < 512; k0 += 32) {
    __syncthreads();
#pragma unroll
    for (int p = 0; p < 2; ++p) {
      int row = p * 64 + arow;
      short8 av = ld8(&A[(size_t)(m0 + row) * 512 + k0 + acol]);
      *reinterpret_cast<short8*>(&Al[row][acol]) = av;
    }
#pragma unroll
    for (int p = 0; p < 4; ++p) {
      int row = p * 32 + srow;
      f32x4 wv = *reinterpret_cast<const f32x4*>(&W[(size_t)(n0 + row) * 512 + k0 + scol]);
      u16x4 wb = { f2bf(wv[0]), f2bf(wv[1]), f2bf(wv[2]), f2bf(wv[3]) };
      *reinterpret_cast<u16x4*>(&Bl[row][scol]) = wb;
    }
    __syncthreads();
    short8 af[4], bfr[4];
#pragma unroll
    for (int i = 0; i < 4; ++i) {
      af[i]  = ld8(&Al[wm + i * 16 + c][g * 8]);
      bfr[i] = ld8(&Bl[wn + i * 16 + c][g * 8]);
    }
#pragma unroll
    for (int i = 0; i < 4; ++i)
#pragma unroll
      for (int j = 0; j < 4; ++j)
        acc[i][j] = __builtin_amdgcn_mfma_f32_16x16x32_bf16(bfr[j], af[i], acc[i][j], 0, 0, 0);
  }

#pragma unroll
  for (int i = 0; i < 4; ++i) {
    int rowm = m0 + wm + i * 16 + c;
#pragma unroll
    for (int j = 0; j < 4; ++j) {
      int nb = n0 + wn + j * 16 + g * 4;
      f32x4 bi = *reinterpret_cast<const f32x4*>(&bias[nb]);
      f32x4 o;
#pragma unroll
      for (int r = 0; r < 4; ++r) o[r] = acc[i][j][r] + bi[r];
      *reinterpret_cast<f32x4*>(&out[(size_t)rowm * 512 + nb]) = o;
    }
  }
}

extern "C" void kernel_launch(void* const* d_in, const int* in_sizes, int n_in,
                              void* d_out, int out_size, void* d_ws, size_t ws_size,
                              hipStream_t stream)
{
  const float* q  = (const float*)d_in[0];
  const float* k  = (const float*)d_in[1];
  const float* v  = (const float*)d_in[2];
  const float* Wq = (const float*)d_in[3];
  const float* bq = (const float*)d_in[4];
  const float* Wk = (const float*)d_in[5];
  const float* bk = (const float*)d_in[6];
  const float* Wv = (const float*)d_in[7];
  const float* bv = (const float*)d_in[8];
  const float* Wo = (const float*)d_in[9];
  const float* bo = (const float*)d_in[10];
  float* out = (float*)d_out;

  unsigned short* ws = (unsigned short*)d_ws;
  unsigned short* Qh = ws;                              // [32][2048][64] (pre-scaled log2e/8)
  unsigned short* Kh = ws + (size_t)4 * 1024 * 1024;    // [32][2048][64]
  unsigned short* Vt = ws + (size_t)8 * 1024 * 1024;    // [32][64][2048]
  unsigned short* at = ws + (size_t)12 * 1024 * 1024;   // [4][2048][512]

  // Determinism hedge (r14 post-timing divergence; r15 confirmed fix).
  hipMemsetAsync(d_ws, 0, (size_t)32 * 1024 * 1024, stream);

  dim3 blk(256);
  proj3<<<dim3(64, 4, 3), blk, 0, stream>>>(q, k, v, Wq, Wk, Wv, bq, bk, bv, Qh, Kh, Vt);
  flash_attn<<<dim3(16, 32), blk, 0, stream>>>(Qh, Kh, Vt, at);
  out_gemm<<<dim3(64, 4), blk, 0, stream>>>(at, Wo, bo, out);
}

// Round 20
// 143.753 us; speedup vs baseline: 1.3214x; 1.3214x over previous
//
#include <hip/hip_runtime.h>
#include <hip/hip_bf16.h>

// MultiHeadAttention: B=4, S=2048, D_MODEL=512, N_HEAD=8, D_K=64
// Pipeline: ws memset hedge -> proj3 (BK=32, 8-wave blocks for occupancy) ->
// flash_attn (r15 verbatim: defer-max, 2 q-tiles/wave) -> out_gemm (r15)

typedef __attribute__((ext_vector_type(8))) short short8;
typedef __attribute__((ext_vector_type(4))) float f32x4;
typedef __attribute__((ext_vector_type(16))) float f32x16;
typedef __attribute__((ext_vector_type(4))) unsigned short u16x4;

union pack_t { int w[4]; short8 v; };

static __device__ __forceinline__ unsigned short f2bf(float x) {
  union { float f; unsigned u; } v; v.f = x;
  unsigned r = v.u + 0x7fffu + ((v.u >> 16) & 1u);
  return (unsigned short)(r >> 16);
}

static __device__ __forceinline__ short8 ld8(const unsigned short* p) {
  return *reinterpret_cast<const short8*>(p);
}

static __device__ __forceinline__ float vmax3(float a, float b, float c) {
  float r; asm("v_max3_f32 %0, %1, %2, %3" : "=v"(r) : "v"(a), "v"(b), "v"(c)); return r;
}

static __device__ __forceinline__ float vexp2(float x) {
  float r; asm("v_exp_f32 %0, %1" : "=v"(r) : "v"(x)); return r;
}

static __device__ __forceinline__ int cvtpk(float a, float b) {
  int r; asm("v_cvt_pk_bf16_f32 %0, %1, %2" : "=v"(r) : "v"(a), "v"(b)); return r;
}

// ---------------------------------------------------------------------------
// Fused projection GEMMs, BK=32 (r15 layout), 512 threads / 8 waves per block
// (2x4 wave grid, each wave 64x32 output) for 2x the resident waves/CU vs the
// 256-thread version — proj3 was latency-bound (r13: all pipes <25% busy,
// occupancy 14%). Epilogue formulas identical to r15 (j range halved).
// ---------------------------------------------------------------------------
__global__ __launch_bounds__(512) void proj3(
    const float* __restrict__ Xq, const float* __restrict__ Xk, const float* __restrict__ Xv,
    const float* __restrict__ Wq, const float* __restrict__ Wk, const float* __restrict__ Wv,
    const float* __restrict__ bq, const float* __restrict__ bk, const float* __restrict__ bv,
    unsigned short* __restrict__ Qh, unsigned short* __restrict__ Kh,
    unsigned short* __restrict__ Vt)
{
  const int z = blockIdx.z;
  const float* X = z == 0 ? Xq : z == 1 ? Xk : Xv;
  const float* W = z == 0 ? Wq : z == 1 ? Wk : Wv;
  const float* bias = z == 0 ? bq : z == 1 ? bk : bv;
  unsigned short* dst = z == 0 ? Qh : z == 1 ? Kh : Vt;
  const int vmode = (z == 2);
  const float oscale = z == 0 ? 0.1803368801f : 1.0f;  // (1/8)*log2(e)

  __shared__ unsigned short Al[128][40];
  __shared__ unsigned short Bl[128][40];
  const int tid = threadIdx.x;
  const int lane = tid & 63;
  const int g = lane >> 4, c = lane & 15;
  const int wave = tid >> 6;                 // 0..7
  const int m0 = blockIdx.x * 128, n0 = blockIdx.y * 128;
  const int wm = (wave & 1) * 64, wn = (wave >> 1) * 32;
  f32x4 acc[4][2] = {};

  const int srow = tid >> 3;                 // 0..63
  const int scol = (tid & 7) * 4;            // 0..28

  for (int k0 = 0; k0 < 512; k0 += 32) {
    __syncthreads();
#pragma unroll
    for (int p = 0; p < 2; ++p) {
      int row = p * 64 + srow;
      f32x4 xv = *reinterpret_cast<const f32x4*>(&X[(size_t)(m0 + row) * 512 + k0 + scol]);
      u16x4 xb = { f2bf(xv[0]), f2bf(xv[1]), f2bf(xv[2]), f2bf(xv[3]) };
      *reinterpret_cast<u16x4*>(&Al[row][scol]) = xb;
      f32x4 wv = *reinterpret_cast<const f32x4*>(&W[(size_t)(n0 + row) * 512 + k0 + scol]);
      u16x4 wb = { f2bf(wv[0]), f2bf(wv[1]), f2bf(wv[2]), f2bf(wv[3]) };
      *reinterpret_cast<u16x4*>(&Bl[row][scol]) = wb;
    }
    __syncthreads();
    short8 af[4], bfr[2];
#pragma unroll
    for (int i = 0; i < 4; ++i)
      af[i] = ld8(&Al[wm + i * 16 + c][g * 8]);
#pragma unroll
    for (int j = 0; j < 2; ++j)
      bfr[j] = ld8(&Bl[wn + j * 16 + c][g * 8]);
    if (vmode) {
#pragma unroll
      for (int i = 0; i < 4; ++i)
#pragma unroll
        for (int j = 0; j < 2; ++j)
          acc[i][j] = __builtin_amdgcn_mfma_f32_16x16x32_bf16(af[i], bfr[j], acc[i][j], 0, 0, 0);
    } else {
#pragma unroll
      for (int i = 0; i < 4; ++i)
#pragma unroll
        for (int j = 0; j < 2; ++j)
          acc[i][j] = __builtin_amdgcn_mfma_f32_16x16x32_bf16(bfr[j], af[i], acc[i][j], 0, 0, 0);
    }
  }

  if (!vmode) {
    // acc[i][j] = C^T block: lane holds s = m0+wm+i*16+c, n = n0+wn+j*16+g*4+r
#pragma unroll
    for (int i = 0; i < 4; ++i) {
      int rowm = m0 + wm + i * 16 + c;
      int b = rowm >> 11, s = rowm & 2047;
#pragma unroll
      for (int j = 0; j < 2; ++j) {
        int nb = n0 + wn + j * 16 + g * 4;
        int h = nb >> 6, d = nb & 63;
        f32x4 bi = *reinterpret_cast<const f32x4*>(&bias[nb]);
        u16x4 o;
#pragma unroll
        for (int r = 0; r < 4; ++r) o[r] = f2bf((acc[i][j][r] + bi[r]) * oscale);
        *reinterpret_cast<u16x4*>(&dst[((size_t)((b * 8 + h) * 2048 + s)) * 64 + d]) = o;
      }
    }
  } else {
    // acc[i][j] = C block: lane holds n = n0+wn+j*16+c, s = m0+wm+i*16+g*4+r
#pragma unroll
    for (int j = 0; j < 2; ++j) {
      int col = n0 + wn + j * 16 + c;
      float bcol = bias[col];
      int h = col >> 6, d = col & 63;
#pragma unroll
      for (int i = 0; i < 4; ++i) {
        int rowm = m0 + wm + i * 16 + g * 4;
        int b = rowm >> 11, s = rowm & 2047;
        u16x4 o;
#pragma unroll
        for (int r = 0; r < 4; ++r) o[r] = f2bf(acc[i][j][r] + bcol);
        *reinterpret_cast<u16x4*>(&dst[((size_t)((b * 8 + h) * 64 + d)) * 2048 + s]) = o;
      }
    }
  }
}

// ---------------------------------------------------------------------------
// flash_attn helpers (r13/r15-verified math, verbatim)
// ---------------------------------------------------------------------------
static __device__ __forceinline__ f32x16 qk_step(
    const short8* qf, short8 k0, short8 k1, short8 k2, short8 k3)
{
  f32x16 sp = {};
  sp = __builtin_amdgcn_mfma_f32_32x32x16_bf16(k0, qf[0], sp, 0, 0, 0);
  sp = __builtin_amdgcn_mfma_f32_32x32x16_bf16(k1, qf[1], sp, 0, 0, 0);
  sp = __builtin_amdgcn_mfma_f32_32x32x16_bf16(k2, qf[2], sp, 0, 0, 0);
  sp = __builtin_amdgcn_mfma_f32_32x32x16_bf16(k3, qf[3], sp, 0, 0, 0);
  return sp;
}

static __device__ __forceinline__ void pv_step(
    short8 v0, short8 v1, short8 v2, short8 v3,
    const pack_t& pf0, const pack_t& pf1, f32x16& acc0, f32x16& acc1)
{
  acc0 = __builtin_amdgcn_mfma_f32_32x32x16_bf16(v0, pf0.v, acc0, 0, 0, 0);
  acc1 = __builtin_amdgcn_mfma_f32_32x32x16_bf16(v1, pf0.v, acc1, 0, 0, 0);
  acc0 = __builtin_amdgcn_mfma_f32_32x32x16_bf16(v2, pf1.v, acc0, 0, 0, 0);
  acc1 = __builtin_amdgcn_mfma_f32_32x32x16_bf16(v3, pf1.v, acc1, 0, 0, 0);
}

static __device__ __forceinline__ void softmax_step(
    const f32x16& sp, float& mrun, float& lrun,
    f32x16& acc0, f32x16& acc1, pack_t& pf0, pack_t& pf1)
{
  float ta = vmax3(sp[0], sp[1], sp[2]);
  float tb = vmax3(sp[3], sp[4], sp[5]);
  float tc = vmax3(sp[6], sp[7], sp[8]);
  float td = vmax3(sp[9], sp[10], sp[11]);
  ta = vmax3(ta, sp[12], sp[13]);
  tb = vmax3(tb, sp[14], sp[15]);
  float tm = fmaxf(vmax3(ta, tb, tc), td);
  float tmx = fmaxf(tm, __shfl_xor(tm, 32));
  if (!__all(tmx <= mrun + 11.0f)) {   // defer-max: P bounded by 2^11 (verified)
    float mn = fmaxf(mrun, tmx);
    float alpha = vexp2(mrun - mn);
    mrun = mn; lrun *= alpha;
#pragma unroll
    for (int i = 0; i < 16; ++i) { acc0[i] *= alpha; acc1[i] *= alpha; }
  }
  float p[16];
  float s0 = 0.f, s1 = 0.f, s2 = 0.f, s3 = 0.f;
#pragma unroll
  for (int i = 0; i < 4; ++i) {
    p[4 * i]     = vexp2(sp[4 * i]     - mrun); s0 += p[4 * i];
    p[4 * i + 1] = vexp2(sp[4 * i + 1] - mrun); s1 += p[4 * i + 1];
    p[4 * i + 2] = vexp2(sp[4 * i + 2] - mrun); s2 += p[4 * i + 2];
    p[4 * i + 3] = vexp2(sp[4 * i + 3] - mrun); s3 += p[4 * i + 3];
  }
  lrun += (s0 + s1) + (s2 + s3);
#pragma unroll
  for (int w = 0; w < 4; ++w) {
    pf0.w[w] = cvtpk(p[2 * w],     p[2 * w + 1]);
    pf1.w[w] = cvtpk(p[8 + 2 * w], p[9 + 2 * w]);
  }
}

// ---------------------------------------------------------------------------
// Flash attention (r15 verbatim): two q-tiles per wave, defer-max softmax.
// ---------------------------------------------------------------------------
__global__ __launch_bounds__(256, 2) void flash_attn(
    const unsigned short* __restrict__ Qh, const unsigned short* __restrict__ Kh,
    const unsigned short* __restrict__ Vt, unsigned short* __restrict__ attn)
{
  __shared__ float Mred[2][2][64];
  __shared__ float Lred[2][2][64];
  __shared__ float AccO[2][64][64];
  const int lane = threadIdx.x & 63;
  const int wave = threadIdx.x >> 6;
  const int qt = wave & 1;
  const int kh = wave >> 1;
  const int lq = lane & 31;
  const int hi = lane >> 5;
  const int n = blockIdx.y * 16 + blockIdx.x;
  const int bh = 4 * (n & 7) + ((n >> 3) & 3);
  const int qw = (n >> 5) * 128 + qt * 64;
  const unsigned short* Qp = Qh + (size_t)bh * 2048 * 64;
  const unsigned short* Kp = Kh + (size_t)bh * 2048 * 64;
  const unsigned short* Vp = Vt + (size_t)bh * 64 * 2048;
  const int blq = (lq & 19) | ((lq & 4) << 1) | ((lq & 8) >> 1);

  short8 qfA[4], qfB[4];
#pragma unroll
  for (int ds = 0; ds < 4; ++ds) {
    qfA[ds] = ld8(Qp + (size_t)(qw + lq) * 64      + ds * 16 + hi * 8);
    qfB[ds] = ld8(Qp + (size_t)(qw + 32 + lq) * 64 + ds * 16 + hi * 8);
  }

  const unsigned short* Kb  = Kp + (size_t)(kh * 1024 + blq) * 64 + hi * 8;
  const unsigned short* Vb0 = Vp + (size_t)lq * 2048        + kh * 1024 + hi * 8;
  const unsigned short* Vb1 = Vp + (size_t)(32 + lq) * 2048 + kh * 1024 + hi * 8;

  short8 kf0, kf1, kf2, kf3, vf0, vf1, vf2, vf3;
#define LOADK(t) do {                                                       \
    const unsigned short* kp_ = Kb + (size_t)(t) * 2048;                    \
    kf0 = ld8(kp_); kf1 = ld8(kp_ + 16); kf2 = ld8(kp_ + 32);               \
    kf3 = ld8(kp_ + 48);                                                    \
  } while (0)
#define LOADV(t) do {                                                       \
    vf0 = ld8(Vb0 + (t) * 32);      vf1 = ld8(Vb1 + (t) * 32);              \
    vf2 = ld8(Vb0 + (t) * 32 + 16); vf3 = ld8(Vb1 + (t) * 32 + 16);         \
  } while (0)

  f32x16 accA0 = {}, accA1 = {}, accB0 = {}, accB1 = {};
  float mrunA = -1e30f, lrunA = 0.f;
  float mrunB = -1e30f, lrunB = 0.f;

  LOADK(0);
  LOADV(0);
  for (int t = 0; t < 32; ++t) {
    __builtin_amdgcn_s_setprio(1);
    f32x16 spA = qk_step(qfA, kf0, kf1, kf2, kf3);
    f32x16 spB = qk_step(qfB, kf0, kf1, kf2, kf3);
    __builtin_amdgcn_s_setprio(0);

    if (t < 31) LOADK(t + 1);

    pack_t pfA0, pfA1, pfB0, pfB1;
    softmax_step(spA, mrunA, lrunA, accA0, accA1, pfA0, pfA1);
    softmax_step(spB, mrunB, lrunB, accB0, accB1, pfB0, pfB1);

    __builtin_amdgcn_s_setprio(1);
    pv_step(vf0, vf1, vf2, vf3, pfA0, pfA1, accA0, accA1);
    pv_step(vf0, vf1, vf2, vf3, pfB0, pfB1, accB0, accB1);
    __builtin_amdgcn_s_setprio(0);

    if (t < 31) LOADV(t + 1);
  }
#undef LOADK
#undef LOADV

  float lfullA = lrunA + __shfl_xor(lrunA, 32);
  float lfullB = lrunB + __shfl_xor(lrunB, 32);
  if (lane < 32) {
    Mred[qt][kh][lq] = mrunA;      Lred[qt][kh][lq] = lfullA;
    Mred[qt][kh][32 + lq] = mrunB; Lred[qt][kh][32 + lq] = lfullB;
  }
  __syncthreads();
  float moA = Mred[qt][kh ^ 1][lq],      loA = Lred[qt][kh ^ 1][lq];
  float moB = Mred[qt][kh ^ 1][32 + lq], loB = Lred[qt][kh ^ 1][32 + lq];
  float mA = fmaxf(mrunA, moA);
  float mB = fmaxf(mrunB, moB);
  float ltotA = lfullA * vexp2(mrunA - mA) + loA * vexp2(moA - mA);
  float ltotB = lfullB * vexp2(mrunB - mB) + loB * vexp2(moB - mB);
  float scA = vexp2(mrunA - mA);
  float scB = vexp2(mrunB - mB);
#pragma unroll
  for (int i = 0; i < 16; ++i) {
    accA0[i] *= scA; accA1[i] *= scA;
    accB0[i] *= scB; accB1[i] *= scB;
  }
  if (kh == 1) {
#pragma unroll
    for (int i = 0; i < 16; ++i) {
      int d = (i & 3) + 8 * (i >> 2) + 4 * hi;
      AccO[qt][d][lq]           = accA0[i];
      AccO[qt][32 + d][lq]      = accA1[i];
      AccO[qt][d][32 + lq]      = accB0[i];
      AccO[qt][32 + d][32 + lq] = accB1[i];
    }
  }
  __syncthreads();
  if (kh == 0) {
#pragma unroll
    for (int i = 0; i < 16; ++i) {
      int d = (i & 3) + 8 * (i >> 2) + 4 * hi;
      AccO[qt][d][lq]           += accA0[i];
      AccO[qt][32 + d][lq]      += accA1[i];
      AccO[qt][d][32 + lq]      += accB0[i];
      AccO[qt][32 + d][32 + lq] += accB1[i];
    }
    float lt = (lane < 32) ? ltotA : ltotB;
    float rl = 1.0f / lt;
    const int b = bh >> 3, h = bh & 7;
    unsigned short* rowp = attn + ((size_t)(b * 2048 + qw + lane)) * 512 + h * 64;
#pragma unroll
    for (int d0 = 0; d0 < 64; d0 += 8) {
      u16x4 o0, o1;
#pragma unroll
      for (int j = 0; j < 4; ++j) {
        o0[j] = f2bf(AccO[qt][d0 + j][lane] * rl);
        o1[j] = f2bf(AccO[qt][d0 + 4 + j][lane] * rl);
      }
      *reinterpret_cast<u16x4*>(rowp + d0) = o0;
      *reinterpret_cast<u16x4*>(rowp + d0 + 4) = o1;
    }
  }
}

// ---------------------------------------------------------------------------
// Output projection (r15-verified, unchanged)
// ---------------------------------------------------------------------------
__global__ __launch_bounds__(256) void out_gemm(
    const unsigned short* __restrict__ A, const float* __restrict__ W,
    const float* __restrict__ bias, float* __restrict__ out)
{
  __shared__ unsigned short Al[128][40];
  __shared__ unsigned short Bl[128][40];
  const int tid = threadIdx.x;
  const int lane = tid & 63;
  const int g = lane >> 4, c = lane & 15;
  const int wave = tid >> 6;
  const int m0 = blockIdx.x * 128, n0 = blockIdx.y * 128;
  const int wm = (wave & 1) * 64, wn = (wave >> 1) * 64;
  f32x4 acc[4][4] = {};

  const int arow = tid >> 2;
  const int acol = (tid & 3) * 8;
  const int srow = tid >> 3;
  const int scol = (tid & 7) * 4;

  for (int k0 = 0; k0 < 512; k0 += 32) {
    __syncthreads();
#pragma unroll
    for (int p = 0; p < 2; ++p) {
      int row = p * 64 + arow;
      short8 av = ld8(&A[(size_t)(m0 + row) * 512 + k0 + acol]);
      *reinterpret_cast<short8*>(&Al[row][acol]) = av;
    }
#pragma unroll
    for (int p = 0; p < 4; ++p) {
      int row = p * 32 + srow;
      f32x4 wv = *reinterpret_cast<const f32x4*>(&W[(size_t)(n0 + row) * 512 + k0 + scol]);
      u16x4 wb = { f2bf(wv[0]), f2bf(wv[1]), f2bf(wv[2]), f2bf(wv[3]) };
      *reinterpret_cast<u16x4*>(&Bl[row][scol]) = wb;
    }
    __syncthreads();
    short8 af[4], bfr[4];
#pragma unroll
    for (int i = 0; i < 4; ++i) {
      af[i]  = ld8(&Al[wm + i * 16 + c][g * 8]);
      bfr[i] = ld8(&Bl[wn + i * 16 + c][g * 8]);
    }
#pragma unroll
    for (int i = 0; i < 4; ++i)
#pragma unroll
      for (int j = 0; j < 4; ++j)
        acc[i][j] = __builtin_amdgcn_mfma_f32_16x16x32_bf16(bfr[j], af[i], acc[i][j], 0, 0, 0);
  }

#pragma unroll
  for (int i = 0; i < 4; ++i) {
    int rowm = m0 + wm + i * 16 + c;
#pragma unroll
    for (int j = 0; j < 4; ++j) {
      int nb = n0 + wn + j * 16 + g * 4;
      f32x4 bi = *reinterpret_cast<const f32x4*>(&bias[nb]);
      f32x4 o;
#pragma unroll
      for (int r = 0; r < 4; ++r) o[r] = acc[i][j][r] + bi[r];
      *reinterpret_cast<f32x4*>(&out[(size_t)rowm * 512 + nb]) = o;
    }
  }
}

extern "C" void kernel_launch(void* const* d_in, const int* in_sizes, int n_in,
                              void* d_out, int out_size, void* d_ws, size_t ws_size,
                              hipStream_t stream)
{
  const float* q  = (const float*)d_in[0];
  const float* k  = (const float*)d_in[1];
  const float* v  = (const float*)d_in[2];
  const float* Wq = (const float*)d_in[3];
  const float* bq = (const float*)d_in[4];
  const float* Wk = (const float*)d_in[5];
  const float* bk = (const float*)d_in[6];
  const float* Wv = (const float*)d_in[7];
  const float* bv = (const float*)d_in[8];
  const float* Wo = (const float*)d_in[9];
  const float* bo = (const float*)d_in[10];
  float* out = (float*)d_out;

  unsigned short* ws = (unsigned short*)d_ws;
  unsigned short* Qh = ws;                              // [32][2048][64] (pre-scaled log2e/8)
  unsigned short* Kh = ws + (size_t)4 * 1024 * 1024;    // [32][2048][64]
  unsigned short* Vt = ws + (size_t)8 * 1024 * 1024;    // [32][64][2048]
  unsigned short* at = ws + (size_t)12 * 1024 * 1024;   // [4][2048][512]

  // Determinism hedge (r14 post-timing divergence; r15 confirmed fix).
  hipMemsetAsync(d_ws, 0, (size_t)32 * 1024 * 1024, stream);

  proj3<<<dim3(64, 4, 3), dim3(512), 0, stream>>>(q, k, v, Wq, Wk, Wv, bq, bk, bv, Qh, Kh, Vt);
  flash_attn<<<dim3(16, 32), dim3(256), 0, stream>>>(Qh, Kh, Vt, at);
  out_gemm<<<dim3(64, 4), dim3(256), 0, stream>>>(at, Wo, bo, out);
}